// Round 1
// baseline (472.609 us; speedup 1.0000x reference)
//
#include <hip/hip_runtime.h>
#include <stdint.h>

#define D 128

// ---------------- degree/count init ----------------
__global__ __launch_bounds__(256) void k_init(float* deg, int* cnt, int n) {
    int i = blockIdx.x * 256 + threadIdx.x;
    if (i < n) { deg[i] = 1.0f; cnt[i] = 0; }
}

// count in-edges per dst + weighted degree
__global__ __launch_bounds__(256) void k_count(const int* __restrict__ ei,
                                               const float* __restrict__ ew,
                                               float* deg, int* cnt, int E) {
    int e = blockIdx.x * 256 + threadIdx.x;
    if (e < E) {
        int d = ei[E + e];
        atomicAdd(&cnt[d], 1);
        atomicAdd(&deg[d], ew[e]);
    }
}

// ---------------- 3-phase exclusive scan ----------------
__global__ __launch_bounds__(256) void k_scanA(const int* __restrict__ cnt,
                                               int* rowstart, int* bsums, int n) {
    __shared__ int tmp[256];
    int tid = threadIdx.x;
    int i = blockIdx.x * 256 + tid;
    int v = (i < n) ? cnt[i] : 0;
    tmp[tid] = v;
    __syncthreads();
    for (int off = 1; off < 256; off <<= 1) {
        int t = (tid >= off) ? tmp[tid - off] : 0;
        __syncthreads();
        tmp[tid] += t;
        __syncthreads();
    }
    if (i < n) rowstart[i] = tmp[tid] - v;   // exclusive
    if (tid == 255) bsums[blockIdx.x] = tmp[255];
}

__global__ __launch_bounds__(256) void k_scanB(const int* __restrict__ bsums,
                                               int* boffs, int nb) {
    __shared__ int tmp[256];
    int tid = threadIdx.x;
    int v = (tid < nb) ? bsums[tid] : 0;
    tmp[tid] = v;
    __syncthreads();
    for (int off = 1; off < 256; off <<= 1) {
        int t = (tid >= off) ? tmp[tid - off] : 0;
        __syncthreads();
        tmp[tid] += t;
        __syncthreads();
    }
    if (tid < nb) boffs[tid] = tmp[tid] - v;  // exclusive
}

__global__ __launch_bounds__(256) void k_scanC(int* rowstart, const int* __restrict__ boffs,
                                               int* fill, const float* __restrict__ deg,
                                               float* dinv, int n) {
    int i = blockIdx.x * 256 + threadIdx.x;
    if (i < n) {
        int rs = rowstart[i] + boffs[blockIdx.x];
        rowstart[i] = rs;
        fill[i] = rs;
        dinv[i] = rsqrtf(deg[i]);   // deg >= 1 always
    }
}

// scatter edges into CSR buckets; precompute norm = dinv[s]*ew*dinv[d]
__global__ __launch_bounds__(256) void k_fill(const int* __restrict__ ei,
                                              const float* __restrict__ ew,
                                              const float* __restrict__ dinv,
                                              int* fill, int* esrc, float* nrm, int E) {
    int e = blockIdx.x * 256 + threadIdx.x;
    if (e < E) {
        int s = ei[e];
        int d = ei[E + e];
        int p = atomicAdd(&fill[d], 1);
        esrc[p] = s;
        nrm[p] = dinv[s] * ew[e] * dinv[d];
    }
}

// ---------------- GEMM: H = (relu?)X @ W,  X:[n,128] W:[128,128] ----------------
// 32 rows/block; W staged in K-halves (32KB) + X tile (padded) in LDS.
__global__ __launch_bounds__(256) void k_gemm(const float* __restrict__ X,
                                              const float* __restrict__ W,
                                              float* __restrict__ H,
                                              int n, int relu_in) {
    __shared__ float sW[64 * 128];   // 32 KB: K-half of W
    __shared__ float sX[32 * 68];    // padded stride 68
    const int tid = threadIdx.x;
    const int tx = tid & 31;         // col group: 4 cols each -> 128
    const int ty = tid >> 5;         // row group: 4 rows each -> 32
    const int row0 = blockIdx.x * 32;

    float acc[4][4];
#pragma unroll
    for (int r = 0; r < 4; ++r)
#pragma unroll
        for (int c = 0; c < 4; ++c) acc[r][c] = 0.0f;

    for (int kb = 0; kb < 2; ++kb) {
        // load W K-half: rows kb*64 .. kb*64+63
        const float4* Wsrc = (const float4*)(W + kb * 64 * 128);
        float4* sW4 = (float4*)sW;
        for (int i = tid; i < 64 * 32; i += 256) sW4[i] = Wsrc[i];
        // load X tile K-half: 32 rows x 64 k
        for (int i = tid; i < 32 * 16; i += 256) {
            int r = i >> 4, s = i & 15;
            int gr = row0 + r;
            float4 v = make_float4(0.f, 0.f, 0.f, 0.f);
            if (gr < n) v = *(const float4*)(X + (size_t)gr * 128 + kb * 64 + s * 4);
            if (relu_in) {
                v.x = fmaxf(v.x, 0.f); v.y = fmaxf(v.y, 0.f);
                v.z = fmaxf(v.z, 0.f); v.w = fmaxf(v.w, 0.f);
            }
            float* dp = &sX[r * 68 + s * 4];
            dp[0] = v.x; dp[1] = v.y; dp[2] = v.z; dp[3] = v.w;
        }
        __syncthreads();
#pragma unroll 8
        for (int k = 0; k < 64; ++k) {
            float4 w = *(const float4*)(&sW[k * 128 + tx * 4]);
            float xv[4];
#pragma unroll
            for (int r = 0; r < 4; ++r) xv[r] = sX[(ty * 4 + r) * 68 + k];
#pragma unroll
            for (int r = 0; r < 4; ++r) {
                acc[r][0] += xv[r] * w.x;
                acc[r][1] += xv[r] * w.y;
                acc[r][2] += xv[r] * w.z;
                acc[r][3] += xv[r] * w.w;
            }
        }
        __syncthreads();
    }
#pragma unroll
    for (int r = 0; r < 4; ++r) {
        int gr = row0 + ty * 4 + r;
        if (gr < n) {
            float4 o;
            o.x = acc[r][0]; o.y = acc[r][1]; o.z = acc[r][2]; o.w = acc[r][3];
            *(float4*)(H + (size_t)gr * 128 + tx * 4) = o;
        }
    }
}

// ---------------- gather: OUT[d][c] = b[c] + dinv[d]^2*H[d][c] + sum nrm*H[src][c] ----------------
// 2 nodes per 256-thread block; 1 col per thread.
__global__ __launch_bounds__(256) void k_gather(const float* __restrict__ H,
                                                const int* __restrict__ esrc,
                                                const float* __restrict__ nrm,
                                                const int* __restrict__ rowstart,
                                                const int* __restrict__ cnt,
                                                const float* __restrict__ dinv,
                                                const float* __restrict__ bias,
                                                float* __restrict__ OUT, int n) {
    int node = blockIdx.x * 2 + (threadIdx.x >> 7);
    int col = threadIdx.x & 127;
    if (node >= n) return;
    int start = rowstart[node];
    int m = cnt[node];
    float di = dinv[node];
    float acc = bias[col] + di * di * H[(size_t)node * 128 + col];
    for (int j = 0; j < m; ++j) {
        int s = esrc[start + j];
        float w = nrm[start + j];
        acc += w * H[(size_t)s * 128 + col];
    }
    OUT[(size_t)node * 128 + col] = acc;
}

extern "C" void kernel_launch(void* const* d_in, const int* in_sizes, int n_in,
                              void* d_out, int out_size, void* d_ws, size_t ws_size,
                              hipStream_t stream) {
    const float* x  = (const float*)d_in[0];
    const int*   ei = (const int*)d_in[1];    // [2,E] int32
    const float* ew = (const float*)d_in[2];
    const float* W1 = (const float*)d_in[3];
    const float* b1 = (const float*)d_in[4];
    const float* W2 = (const float*)d_in[5];
    const float* b2 = (const float*)d_in[6];
    float* out = (float*)d_out;

    const int N = in_sizes[0] / D;
    const int E = in_sizes[2];

    // workspace carve (256B aligned)
    char* p = (char*)d_ws;
    auto alloc = [&](size_t bytes) {
        void* r = (void*)p;
        p += (bytes + 255) & ~(size_t)255;
        return r;
    };
    float* deg      = (float*)alloc((size_t)N * 4);
    float* dinv     = (float*)alloc((size_t)N * 4);
    int*   cnt      = (int*)alloc((size_t)N * 4);
    int*   rowstart = (int*)alloc((size_t)N * 4);
    int*   fill     = (int*)alloc((size_t)N * 4);
    int*   bsums    = (int*)alloc(1024 * 4);
    int*   boffs    = (int*)alloc(1024 * 4);
    int*   esrc     = (int*)alloc((size_t)E * 4);
    float* nrm      = (float*)alloc((size_t)E * 4);
    float* B1       = (float*)alloc((size_t)N * D * 4);  // H buffer (reused layer2)
    float* B2       = (float*)alloc((size_t)N * D * 4);  // AGG1 buffer

    const int nb = (N + 255) / 256;
    const int eb = (E + 255) / 256;
    const int gb = (N + 31) / 32;
    const int hb = (N + 1) / 2;

    k_init<<<nb, 256, 0, stream>>>(deg, cnt, N);
    k_count<<<eb, 256, 0, stream>>>(ei, ew, deg, cnt, E);
    k_scanA<<<nb, 256, 0, stream>>>(cnt, rowstart, bsums, N);
    k_scanB<<<1, 256, 0, stream>>>(bsums, boffs, nb);
    k_scanC<<<nb, 256, 0, stream>>>(rowstart, boffs, fill, deg, dinv, N);
    k_fill<<<eb, 256, 0, stream>>>(ei, ew, dinv, fill, esrc, nrm, E);

    // layer 1
    k_gemm<<<gb, 256, 0, stream>>>(x, W1, B1, N, 0);
    k_gather<<<hb, 256, 0, stream>>>(B1, esrc, nrm, rowstart, cnt, dinv, b1, B2, N);
    // layer 2 (relu fused into GEMM input load)
    k_gemm<<<gb, 256, 0, stream>>>(B2, W2, B1, N, 1);
    k_gather<<<hb, 256, 0, stream>>>(B1, esrc, nrm, rowstart, cnt, dinv, b2, out, N);
}

// Round 2
// 342.124 us; speedup vs baseline: 1.3814x; 1.3814x over previous
//
#include <hip/hip_runtime.h>
#include <stdint.h>

#define D 128

// ---------------- degree/count init ----------------
__global__ __launch_bounds__(256) void k_init(float* deg, int* cnt, int n) {
    int i = blockIdx.x * 256 + threadIdx.x;
    if (i < n) { deg[i] = 1.0f; cnt[i] = 0; }
}

// count in-edges per dst + weighted degree
__global__ __launch_bounds__(256) void k_count(const int* __restrict__ ei,
                                               const float* __restrict__ ew,
                                               float* deg, int* cnt, int E) {
    int e = blockIdx.x * 256 + threadIdx.x;
    if (e < E) {
        int d = ei[E + e];
        atomicAdd(&cnt[d], 1);
        atomicAdd(&deg[d], ew[e]);
    }
}

// ---------------- 3-phase exclusive scan ----------------
__global__ __launch_bounds__(256) void k_scanA(const int* __restrict__ cnt,
                                               int* rowstart, int* bsums, int n) {
    __shared__ int tmp[256];
    int tid = threadIdx.x;
    int i = blockIdx.x * 256 + tid;
    int v = (i < n) ? cnt[i] : 0;
    tmp[tid] = v;
    __syncthreads();
    for (int off = 1; off < 256; off <<= 1) {
        int t = (tid >= off) ? tmp[tid - off] : 0;
        __syncthreads();
        tmp[tid] += t;
        __syncthreads();
    }
    if (i < n) rowstart[i] = tmp[tid] - v;   // exclusive
    if (tid == 255) bsums[blockIdx.x] = tmp[255];
}

__global__ __launch_bounds__(256) void k_scanB(const int* __restrict__ bsums,
                                               int* boffs, int nb) {
    __shared__ int tmp[256];
    int tid = threadIdx.x;
    int v = (tid < nb) ? bsums[tid] : 0;
    tmp[tid] = v;
    __syncthreads();
    for (int off = 1; off < 256; off <<= 1) {
        int t = (tid >= off) ? tmp[tid - off] : 0;
        __syncthreads();
        tmp[tid] += t;
        __syncthreads();
    }
    if (tid < nb) boffs[tid] = tmp[tid] - v;  // exclusive
}

__global__ __launch_bounds__(256) void k_scanC(int* rowstart, const int* __restrict__ boffs,
                                               int* fill, const float* __restrict__ deg,
                                               float* dinv, int n) {
    int i = blockIdx.x * 256 + threadIdx.x;
    if (i < n) {
        int rs = rowstart[i] + boffs[blockIdx.x];
        rowstart[i] = rs;
        fill[i] = rs;
        dinv[i] = rsqrtf(deg[i]);   // deg >= 1 always
    }
}

// scatter edges into CSR buckets; precompute norm = dinv[s]*ew*dinv[d]
__global__ __launch_bounds__(256) void k_fill(const int* __restrict__ ei,
                                              const float* __restrict__ ew,
                                              const float* __restrict__ dinv,
                                              int* fill, int* esrc, float* nrm, int E) {
    int e = blockIdx.x * 256 + threadIdx.x;
    if (e < E) {
        int s = ei[e];
        int d = ei[E + e];
        int p = atomicAdd(&fill[d], 1);
        esrc[p] = s;
        nrm[p] = dinv[s] * ew[e] * dinv[d];
    }
}

// ---------------- GEMM: H = (relu?)X @ W,  X:[n,128] W:[128,128] ----------------
// 32 rows/block; W staged in K-halves (32KB) + X tile (padded) in LDS.
__global__ __launch_bounds__(256) void k_gemm(const float* __restrict__ X,
                                              const float* __restrict__ W,
                                              float* __restrict__ H,
                                              int n, int relu_in) {
    __shared__ float sW[64 * 128];   // 32 KB: K-half of W
    __shared__ float sX[32 * 68];    // padded stride 68
    const int tid = threadIdx.x;
    const int tx = tid & 31;         // col group: 4 cols each -> 128
    const int ty = tid >> 5;         // row group: 4 rows each -> 32
    const int row0 = blockIdx.x * 32;

    float acc[4][4];
#pragma unroll
    for (int r = 0; r < 4; ++r)
#pragma unroll
        for (int c = 0; c < 4; ++c) acc[r][c] = 0.0f;

    for (int kb = 0; kb < 2; ++kb) {
        // load W K-half: rows kb*64 .. kb*64+63
        const float4* Wsrc = (const float4*)(W + kb * 64 * 128);
        float4* sW4 = (float4*)sW;
        for (int i = tid; i < 64 * 32; i += 256) sW4[i] = Wsrc[i];
        // load X tile K-half: 32 rows x 64 k
        for (int i = tid; i < 32 * 16; i += 256) {
            int r = i >> 4, s = i & 15;
            int gr = row0 + r;
            float4 v = make_float4(0.f, 0.f, 0.f, 0.f);
            if (gr < n) v = *(const float4*)(X + (size_t)gr * 128 + kb * 64 + s * 4);
            if (relu_in) {
                v.x = fmaxf(v.x, 0.f); v.y = fmaxf(v.y, 0.f);
                v.z = fmaxf(v.z, 0.f); v.w = fmaxf(v.w, 0.f);
            }
            float* dp = &sX[r * 68 + s * 4];
            dp[0] = v.x; dp[1] = v.y; dp[2] = v.z; dp[3] = v.w;
        }
        __syncthreads();
#pragma unroll 8
        for (int k = 0; k < 64; ++k) {
            float4 w = *(const float4*)(&sW[k * 128 + tx * 4]);
            float xv[4];
#pragma unroll
            for (int r = 0; r < 4; ++r) xv[r] = sX[(ty * 4 + r) * 68 + k];
#pragma unroll
            for (int r = 0; r < 4; ++r) {
                acc[r][0] += xv[r] * w.x;
                acc[r][1] += xv[r] * w.y;
                acc[r][2] += xv[r] * w.z;
                acc[r][3] += xv[r] * w.w;
            }
        }
        __syncthreads();
    }
#pragma unroll
    for (int r = 0; r < 4; ++r) {
        int gr = row0 + ty * 4 + r;
        if (gr < n) {
            float4 o;
            o.x = acc[r][0]; o.y = acc[r][1]; o.z = acc[r][2]; o.w = acc[r][3];
            *(float4*)(H + (size_t)gr * 128 + tx * 4) = o;
        }
    }
}

// ---------------- gather: OUT[d][c] = b[c] + dinv[d]^2*H[d][c] + sum nrm*H[src][c] ----------------
// 8 nodes per 256-thread block; 32 threads/node, float4 (4 cols) per thread.
// Edge loop unrolled x4 for memory-level parallelism.
__global__ __launch_bounds__(256) void k_gather(const float4* __restrict__ H4,
                                                const int* __restrict__ esrc,
                                                const float* __restrict__ nrm,
                                                const int* __restrict__ rowstart,
                                                const int* __restrict__ cnt,
                                                const float* __restrict__ dinv,
                                                const float4* __restrict__ bias4,
                                                float4* __restrict__ OUT4, int n) {
    const int lane = threadIdx.x & 31;                 // col group (4 cols)
    const int node = blockIdx.x * 8 + (threadIdx.x >> 5);
    if (node >= n) return;
    const int start = rowstart[node];
    const int m = cnt[node];
    const float di = dinv[node];
    const float dii = di * di;

    float4 b = bias4[lane];
    float4 h = H4[(size_t)node * 32 + lane];
    float ax = b.x + dii * h.x;
    float ay = b.y + dii * h.y;
    float az = b.z + dii * h.z;
    float aw = b.w + dii * h.w;

    int j = 0;
    for (; j + 4 <= m; j += 4) {
        const int base = start + j;
        int s0 = esrc[base + 0], s1 = esrc[base + 1];
        int s2 = esrc[base + 2], s3 = esrc[base + 3];
        float w0 = nrm[base + 0], w1 = nrm[base + 1];
        float w2 = nrm[base + 2], w3 = nrm[base + 3];
        float4 v0 = H4[(size_t)s0 * 32 + lane];
        float4 v1 = H4[(size_t)s1 * 32 + lane];
        float4 v2 = H4[(size_t)s2 * 32 + lane];
        float4 v3 = H4[(size_t)s3 * 32 + lane];
        ax += w0 * v0.x; ay += w0 * v0.y; az += w0 * v0.z; aw += w0 * v0.w;
        ax += w1 * v1.x; ay += w1 * v1.y; az += w1 * v1.z; aw += w1 * v1.w;
        ax += w2 * v2.x; ay += w2 * v2.y; az += w2 * v2.z; aw += w2 * v2.w;
        ax += w3 * v3.x; ay += w3 * v3.y; az += w3 * v3.z; aw += w3 * v3.w;
    }
    for (; j < m; ++j) {
        int s = esrc[start + j];
        float w = nrm[start + j];
        float4 v = H4[(size_t)s * 32 + lane];
        ax += w * v.x; ay += w * v.y; az += w * v.z; aw += w * v.w;
    }
    float4 o; o.x = ax; o.y = ay; o.z = az; o.w = aw;
    OUT4[(size_t)node * 32 + lane] = o;
}

extern "C" void kernel_launch(void* const* d_in, const int* in_sizes, int n_in,
                              void* d_out, int out_size, void* d_ws, size_t ws_size,
                              hipStream_t stream) {
    const float* x  = (const float*)d_in[0];
    const int*   ei = (const int*)d_in[1];    // [2,E] int32
    const float* ew = (const float*)d_in[2];
    const float* W1 = (const float*)d_in[3];
    const float* b1 = (const float*)d_in[4];
    const float* W2 = (const float*)d_in[5];
    const float* b2 = (const float*)d_in[6];
    float* out = (float*)d_out;

    const int N = in_sizes[0] / D;
    const int E = in_sizes[2];

    // workspace carve (256B aligned)
    char* p = (char*)d_ws;
    auto alloc = [&](size_t bytes) {
        void* r = (void*)p;
        p += (bytes + 255) & ~(size_t)255;
        return r;
    };
    float* deg      = (float*)alloc((size_t)N * 4);
    float* dinv     = (float*)alloc((size_t)N * 4);
    int*   cnt      = (int*)alloc((size_t)N * 4);
    int*   rowstart = (int*)alloc((size_t)N * 4);
    int*   fill     = (int*)alloc((size_t)N * 4);
    int*   bsums    = (int*)alloc(1024 * 4);
    int*   boffs    = (int*)alloc(1024 * 4);
    int*   esrc     = (int*)alloc((size_t)E * 4);
    float* nrm      = (float*)alloc((size_t)E * 4);
    float* B1       = (float*)alloc((size_t)N * D * 4);  // H buffer (reused layer2)
    float* B2       = (float*)alloc((size_t)N * D * 4);  // AGG1 buffer

    const int nb = (N + 255) / 256;
    const int eb = (E + 255) / 256;
    const int gb = (N + 31) / 32;
    const int hb = (N + 7) / 8;

    k_init<<<nb, 256, 0, stream>>>(deg, cnt, N);
    k_count<<<eb, 256, 0, stream>>>(ei, ew, deg, cnt, E);
    k_scanA<<<nb, 256, 0, stream>>>(cnt, rowstart, bsums, N);
    k_scanB<<<1, 256, 0, stream>>>(bsums, boffs, nb);
    k_scanC<<<nb, 256, 0, stream>>>(rowstart, boffs, fill, deg, dinv, N);
    k_fill<<<eb, 256, 0, stream>>>(ei, ew, dinv, fill, esrc, nrm, E);

    // layer 1
    k_gemm<<<gb, 256, 0, stream>>>(x, W1, B1, N, 0);
    k_gather<<<hb, 256, 0, stream>>>((const float4*)B1, esrc, nrm, rowstart, cnt, dinv,
                                     (const float4*)b1, (float4*)B2, N);
    // layer 2 (relu fused into GEMM input load)
    k_gemm<<<gb, 256, 0, stream>>>(B2, W2, B1, N, 1);
    k_gather<<<hb, 256, 0, stream>>>((const float4*)B1, esrc, nrm, rowstart, cnt, dinv,
                                     (const float4*)b2, (float4*)out, N);
}

// Round 3
// 289.615 us; speedup vs baseline: 1.6319x; 1.1813x over previous
//
#include <hip/hip_runtime.h>
#include <stdint.h>

#define D 128

// count edges per dst + accumulate weighted degree, ONE packed 64-bit atomic.
// high 32 bits: count; low 32 bits: sum(ew) in 2^-24 fixed point (sum < 256 safe).
// Returned high word = this edge's rank within its dst bucket.
__global__ __launch_bounds__(256) void k_count(const int* __restrict__ ei,
                                               const float* __restrict__ ew,
                                               unsigned long long* __restrict__ pk,
                                               int* __restrict__ rank, int E) {
    int e = blockIdx.x * 256 + threadIdx.x;
    if (e < E) {
        int d = ei[E + e];
        unsigned int fx = (unsigned int)(ew[e] * 16777216.0f);
        unsigned long long old =
            atomicAdd(&pk[d], (1ULL << 32) | (unsigned long long)fx);
        rank[e] = (int)(old >> 32);
    }
}

// ---------------- 3-phase exclusive scan over packed counts ----------------
__global__ __launch_bounds__(256) void k_scanA(const unsigned long long* __restrict__ pk,
                                               int* rowstart, int* bsums, int n) {
    __shared__ int tmp[256];
    int tid = threadIdx.x;
    int i = blockIdx.x * 256 + tid;
    int v = (i < n) ? (int)(pk[i] >> 32) : 0;
    tmp[tid] = v;
    __syncthreads();
    for (int off = 1; off < 256; off <<= 1) {
        int t = (tid >= off) ? tmp[tid - off] : 0;
        __syncthreads();
        tmp[tid] += t;
        __syncthreads();
    }
    if (i < n) rowstart[i] = tmp[tid] - v;   // exclusive
    if (tid == 255) bsums[blockIdx.x] = tmp[255];
}

__global__ __launch_bounds__(256) void k_scanB(const int* __restrict__ bsums,
                                               int* boffs, int nb) {
    __shared__ int tmp[256];
    int tid = threadIdx.x;
    int v = (tid < nb) ? bsums[tid] : 0;
    tmp[tid] = v;
    __syncthreads();
    for (int off = 1; off < 256; off <<= 1) {
        int t = (tid >= off) ? tmp[tid - off] : 0;
        __syncthreads();
        tmp[tid] += t;
        __syncthreads();
    }
    if (tid < nb) boffs[tid] = tmp[tid] - v;  // exclusive
}

__global__ __launch_bounds__(256) void k_scanC(int* rowstart, const int* __restrict__ boffs,
                                               const unsigned long long* __restrict__ pk,
                                               int* cnt, float* dinv, int n) {
    int i = blockIdx.x * 256 + threadIdx.x;
    if (i < n) {
        rowstart[i] = rowstart[i] + boffs[blockIdx.x];
        unsigned long long v = pk[i];
        cnt[i] = (int)(v >> 32);
        float deg = 1.0f + (float)(unsigned int)(v & 0xFFFFFFFFu) * (1.0f / 16777216.0f);
        dinv[i] = rsqrtf(deg);
    }
}

// place edges into CSR: NO atomics (position = rowstart[d] + rank[e]).
__global__ __launch_bounds__(256) void k_edges(const int* __restrict__ ei,
                                               const float* __restrict__ ew,
                                               const float* __restrict__ dinv,
                                               const int* __restrict__ rowstart,
                                               const int* __restrict__ rank,
                                               int* __restrict__ esrc,
                                               float* __restrict__ nrm, int E) {
    int e = blockIdx.x * 256 + threadIdx.x;
    if (e < E) {
        int s = ei[e];
        int d = ei[E + e];
        int p = rowstart[d] + rank[e];
        esrc[p] = s;
        nrm[p] = dinv[s] * ew[e] * dinv[d];
    }
}

// ---------------- GEMM: H = (relu?)X @ W,  X:[n,128] W:[128,128] ----------------
__global__ __launch_bounds__(256) void k_gemm(const float* __restrict__ X,
                                              const float* __restrict__ W,
                                              float* __restrict__ H,
                                              int n, int relu_in) {
    __shared__ float sW[64 * 128];   // 32 KB: K-half of W
    __shared__ float sX[32 * 68];    // padded stride 68
    const int tid = threadIdx.x;
    const int tx = tid & 31;         // col group: 4 cols each -> 128
    const int ty = tid >> 5;         // row group: 4 rows each -> 32
    const int row0 = blockIdx.x * 32;

    float acc[4][4];
#pragma unroll
    for (int r = 0; r < 4; ++r)
#pragma unroll
        for (int c = 0; c < 4; ++c) acc[r][c] = 0.0f;

    for (int kb = 0; kb < 2; ++kb) {
        const float4* Wsrc = (const float4*)(W + kb * 64 * 128);
        float4* sW4 = (float4*)sW;
        for (int i = tid; i < 64 * 32; i += 256) sW4[i] = Wsrc[i];
        for (int i = tid; i < 32 * 16; i += 256) {
            int r = i >> 4, s = i & 15;
            int gr = row0 + r;
            float4 v = make_float4(0.f, 0.f, 0.f, 0.f);
            if (gr < n) v = *(const float4*)(X + (size_t)gr * 128 + kb * 64 + s * 4);
            if (relu_in) {
                v.x = fmaxf(v.x, 0.f); v.y = fmaxf(v.y, 0.f);
                v.z = fmaxf(v.z, 0.f); v.w = fmaxf(v.w, 0.f);
            }
            float* dp = &sX[r * 68 + s * 4];
            dp[0] = v.x; dp[1] = v.y; dp[2] = v.z; dp[3] = v.w;
        }
        __syncthreads();
#pragma unroll 8
        for (int k = 0; k < 64; ++k) {
            float4 w = *(const float4*)(&sW[k * 128 + tx * 4]);
            float xv[4];
#pragma unroll
            for (int r = 0; r < 4; ++r) xv[r] = sX[(ty * 4 + r) * 68 + k];
#pragma unroll
            for (int r = 0; r < 4; ++r) {
                acc[r][0] += xv[r] * w.x;
                acc[r][1] += xv[r] * w.y;
                acc[r][2] += xv[r] * w.z;
                acc[r][3] += xv[r] * w.w;
            }
        }
        __syncthreads();
    }
#pragma unroll
    for (int r = 0; r < 4; ++r) {
        int gr = row0 + ty * 4 + r;
        if (gr < n) {
            float4 o;
            o.x = acc[r][0]; o.y = acc[r][1]; o.z = acc[r][2]; o.w = acc[r][3];
            *(float4*)(H + (size_t)gr * 128 + tx * 4) = o;
        }
    }
}

// ---------------- gather: OUT[d][c] = b[c] + dinv[d]^2*H[d][c] + sum nrm*H[src][c] ----------------
// 8 nodes per 256-thread block; 32 threads/node, float4 per thread, x4 unroll for MLP.
__global__ __launch_bounds__(256) void k_gather(const float4* __restrict__ H4,
                                                const int* __restrict__ esrc,
                                                const float* __restrict__ nrm,
                                                const int* __restrict__ rowstart,
                                                const int* __restrict__ cnt,
                                                const float* __restrict__ dinv,
                                                const float4* __restrict__ bias4,
                                                float4* __restrict__ OUT4, int n) {
    const int lane = threadIdx.x & 31;
    const int node = blockIdx.x * 8 + (threadIdx.x >> 5);
    if (node >= n) return;
    const int start = rowstart[node];
    const int m = cnt[node];
    const float di = dinv[node];
    const float dii = di * di;

    float4 b = bias4[lane];
    float4 h = H4[(size_t)node * 32 + lane];
    float ax = b.x + dii * h.x;
    float ay = b.y + dii * h.y;
    float az = b.z + dii * h.z;
    float aw = b.w + dii * h.w;

    int j = 0;
    for (; j + 4 <= m; j += 4) {
        const int base = start + j;
        int s0 = esrc[base + 0], s1 = esrc[base + 1];
        int s2 = esrc[base + 2], s3 = esrc[base + 3];
        float w0 = nrm[base + 0], w1 = nrm[base + 1];
        float w2 = nrm[base + 2], w3 = nrm[base + 3];
        float4 v0 = H4[(size_t)s0 * 32 + lane];
        float4 v1 = H4[(size_t)s1 * 32 + lane];
        float4 v2 = H4[(size_t)s2 * 32 + lane];
        float4 v3 = H4[(size_t)s3 * 32 + lane];
        ax += w0 * v0.x; ay += w0 * v0.y; az += w0 * v0.z; aw += w0 * v0.w;
        ax += w1 * v1.x; ay += w1 * v1.y; az += w1 * v1.z; aw += w1 * v1.w;
        ax += w2 * v2.x; ay += w2 * v2.y; az += w2 * v2.z; aw += w2 * v2.w;
        ax += w3 * v3.x; ay += w3 * v3.y; az += w3 * v3.z; aw += w3 * v3.w;
    }
    for (; j < m; ++j) {
        int s = esrc[start + j];
        float w = nrm[start + j];
        float4 v = H4[(size_t)s * 32 + lane];
        ax += w * v.x; ay += w * v.y; az += w * v.z; aw += w * v.w;
    }
    float4 o; o.x = ax; o.y = ay; o.z = az; o.w = aw;
    OUT4[(size_t)node * 32 + lane] = o;
}

extern "C" void kernel_launch(void* const* d_in, const int* in_sizes, int n_in,
                              void* d_out, int out_size, void* d_ws, size_t ws_size,
                              hipStream_t stream) {
    const float* x  = (const float*)d_in[0];
    const int*   ei = (const int*)d_in[1];    // [2,E] int32
    const float* ew = (const float*)d_in[2];
    const float* W1 = (const float*)d_in[3];
    const float* b1 = (const float*)d_in[4];
    const float* W2 = (const float*)d_in[5];
    const float* b2 = (const float*)d_in[6];
    float* out = (float*)d_out;

    const int N = in_sizes[0] / D;
    const int E = in_sizes[2];

    // workspace carve (256B aligned)
    char* p = (char*)d_ws;
    auto alloc = [&](size_t bytes) {
        void* r = (void*)p;
        p += (bytes + 255) & ~(size_t)255;
        return r;
    };
    unsigned long long* pk = (unsigned long long*)alloc((size_t)N * 8);
    float* dinv     = (float*)alloc((size_t)N * 4);
    int*   cnt      = (int*)alloc((size_t)N * 4);
    int*   rowstart = (int*)alloc((size_t)N * 4);
    int*   bsums    = (int*)alloc(1024 * 4);
    int*   boffs    = (int*)alloc(1024 * 4);
    int*   rank     = (int*)alloc((size_t)E * 4);
    int*   esrc     = (int*)alloc((size_t)E * 4);
    float* nrm      = (float*)alloc((size_t)E * 4);
    float* B1       = (float*)alloc((size_t)N * D * 4);  // H buffer (reused layer2)
    float* B2       = (float*)alloc((size_t)N * D * 4);  // AGG1 buffer

    const int nb = (N + 255) / 256;
    const int eb = (E + 255) / 256;
    const int gb = (N + 31) / 32;
    const int hb = (N + 7) / 8;

    hipMemsetAsync(pk, 0, (size_t)N * 8, stream);
    k_count<<<eb, 256, 0, stream>>>(ei, ew, pk, rank, E);
    k_scanA<<<nb, 256, 0, stream>>>(pk, rowstart, bsums, N);
    k_scanB<<<1, 256, 0, stream>>>(bsums, boffs, nb);
    k_scanC<<<nb, 256, 0, stream>>>(rowstart, boffs, pk, cnt, dinv, N);
    k_edges<<<eb, 256, 0, stream>>>(ei, ew, dinv, rowstart, rank, esrc, nrm, E);

    // layer 1
    k_gemm<<<gb, 256, 0, stream>>>(x, W1, B1, N, 0);
    k_gather<<<hb, 256, 0, stream>>>((const float4*)B1, esrc, nrm, rowstart, cnt, dinv,
                                     (const float4*)b1, (float4*)B2, N);
    // layer 2 (relu fused into GEMM input load)
    k_gemm<<<gb, 256, 0, stream>>>(B2, W2, B1, N, 1);
    k_gather<<<hb, 256, 0, stream>>>((const float4*)B1, esrc, nrm, rowstart, cnt, dinv,
                                     (const float4*)b2, (float4*)out, N);
}

// Round 4
// 254.892 us; speedup vs baseline: 1.8542x; 1.1362x over previous
//
#include <hip/hip_runtime.h>
#include <stdint.h>

#define D 128

__device__ inline float bf2f(unsigned short u) {
    return __uint_as_float((unsigned)u << 16);
}
__device__ inline unsigned short f2bf(float f) {
    unsigned u = __float_as_uint(f);
    return (unsigned short)((u + 0x7FFF + ((u >> 16) & 1)) >> 16);  // RNE
}

// count edges per dst + accumulate weighted degree, ONE packed 64-bit atomic.
// high 32 bits: count; low 32 bits: sum(ew) in 2^-24 fixed point.
// Returned high word = this edge's rank within its dst bucket.
__global__ __launch_bounds__(256) void k_count(const int* __restrict__ ei,
                                               const float* __restrict__ ew,
                                               unsigned long long* __restrict__ pk,
                                               int* __restrict__ rank, int E) {
    int e = blockIdx.x * 256 + threadIdx.x;
    if (e < E) {
        int d = ei[E + e];
        unsigned int fx = (unsigned int)(ew[e] * 16777216.0f);
        unsigned long long old =
            atomicAdd(&pk[d], (1ULL << 32) | (unsigned long long)fx);
        rank[e] = (int)(old >> 32);
    }
}

// ---------------- 3-phase exclusive scan over packed counts ----------------
__global__ __launch_bounds__(256) void k_scanA(const unsigned long long* __restrict__ pk,
                                               int* rowstart, int* bsums, int n) {
    __shared__ int tmp[256];
    int tid = threadIdx.x;
    int i = blockIdx.x * 256 + tid;
    int v = (i < n) ? (int)(pk[i] >> 32) : 0;
    tmp[tid] = v;
    __syncthreads();
    for (int off = 1; off < 256; off <<= 1) {
        int t = (tid >= off) ? tmp[tid - off] : 0;
        __syncthreads();
        tmp[tid] += t;
        __syncthreads();
    }
    if (i < n) rowstart[i] = tmp[tid] - v;   // exclusive
    if (tid == 255) bsums[blockIdx.x] = tmp[255];
}

__global__ __launch_bounds__(256) void k_scanB(const int* __restrict__ bsums,
                                               int* boffs, int nb) {
    __shared__ int tmp[256];
    int tid = threadIdx.x;
    int v = (tid < nb) ? bsums[tid] : 0;
    tmp[tid] = v;
    __syncthreads();
    for (int off = 1; off < 256; off <<= 1) {
        int t = (tid >= off) ? tmp[tid - off] : 0;
        __syncthreads();
        tmp[tid] += t;
        __syncthreads();
    }
    if (tid < nb) boffs[tid] = tmp[tid] - v;  // exclusive
}

__global__ __launch_bounds__(256) void k_scanC(int* rowstart, const int* __restrict__ boffs,
                                               const unsigned long long* __restrict__ pk,
                                               int* cnt, float* dinv, int n) {
    int i = blockIdx.x * 256 + threadIdx.x;
    if (i < n) {
        rowstart[i] = rowstart[i] + boffs[blockIdx.x];
        unsigned long long v = pk[i];
        cnt[i] = (int)(v >> 32);
        float deg = 1.0f + (float)(unsigned int)(v & 0xFFFFFFFFu) * (1.0f / 16777216.0f);
        dinv[i] = rsqrtf(deg);
    }
}

// place edges into CSR: NO atomics (position = rowstart[d] + rank[e]).
__global__ __launch_bounds__(256) void k_edges(const int* __restrict__ ei,
                                               const float* __restrict__ ew,
                                               const float* __restrict__ dinv,
                                               const int* __restrict__ rowstart,
                                               const int* __restrict__ rank,
                                               int* __restrict__ esrc,
                                               float* __restrict__ nrm, int E) {
    int e = blockIdx.x * 256 + threadIdx.x;
    if (e < E) {
        int s = ei[e];
        int d = ei[E + e];
        int p = rowstart[d] + rank[e];
        esrc[p] = s;
        nrm[p] = dinv[s] * ew[e] * dinv[d];
    }
}

// ---------------- GEMM: H = (relu?)X @ W,  X:[n,128] W:[128,128], H stored bf16 ----------------
__global__ __launch_bounds__(256) void k_gemm(const float* __restrict__ X,
                                              const float* __restrict__ W,
                                              unsigned short* __restrict__ H,
                                              int n, int relu_in) {
    __shared__ float sW[64 * 128];   // 32 KB: K-half of W
    __shared__ float sX[32 * 68];    // padded stride 68
    const int tid = threadIdx.x;
    const int tx = tid & 31;         // col group: 4 cols each -> 128
    const int ty = tid >> 5;         // row group: 4 rows each -> 32
    const int row0 = blockIdx.x * 32;

    float acc[4][4];
#pragma unroll
    for (int r = 0; r < 4; ++r)
#pragma unroll
        for (int c = 0; c < 4; ++c) acc[r][c] = 0.0f;

    for (int kb = 0; kb < 2; ++kb) {
        const float4* Wsrc = (const float4*)(W + kb * 64 * 128);
        float4* sW4 = (float4*)sW;
        for (int i = tid; i < 64 * 32; i += 256) sW4[i] = Wsrc[i];
        for (int i = tid; i < 32 * 16; i += 256) {
            int r = i >> 4, s = i & 15;
            int gr = row0 + r;
            float4 v = make_float4(0.f, 0.f, 0.f, 0.f);
            if (gr < n) v = *(const float4*)(X + (size_t)gr * 128 + kb * 64 + s * 4);
            if (relu_in) {
                v.x = fmaxf(v.x, 0.f); v.y = fmaxf(v.y, 0.f);
                v.z = fmaxf(v.z, 0.f); v.w = fmaxf(v.w, 0.f);
            }
            float* dp = &sX[r * 68 + s * 4];
            dp[0] = v.x; dp[1] = v.y; dp[2] = v.z; dp[3] = v.w;
        }
        __syncthreads();
#pragma unroll 8
        for (int k = 0; k < 64; ++k) {
            float4 w = *(const float4*)(&sW[k * 128 + tx * 4]);
            float xv[4];
#pragma unroll
            for (int r = 0; r < 4; ++r) xv[r] = sX[(ty * 4 + r) * 68 + k];
#pragma unroll
            for (int r = 0; r < 4; ++r) {
                acc[r][0] += xv[r] * w.x;
                acc[r][1] += xv[r] * w.y;
                acc[r][2] += xv[r] * w.z;
                acc[r][3] += xv[r] * w.w;
            }
        }
        __syncthreads();
    }
#pragma unroll
    for (int r = 0; r < 4; ++r) {
        int gr = row0 + ty * 4 + r;
        if (gr < n) {
            ushort4 o;
            o.x = f2bf(acc[r][0]); o.y = f2bf(acc[r][1]);
            o.z = f2bf(acc[r][2]); o.w = f2bf(acc[r][3]);
            *(ushort4*)(H + (size_t)gr * 128 + tx * 4) = o;
        }
    }
}

// ---------------- gather: OUT[d][c] = b[c] + dinv[d]^2*H[d][c] + sum nrm*H[src][c] ----------------
// 8 nodes per 256-thread block; 32 threads/node, 4 bf16 cols (8B) per thread, x4 unroll.
__global__ __launch_bounds__(256) void k_gather(const ushort4* __restrict__ H4,
                                                const int* __restrict__ esrc,
                                                const float* __restrict__ nrm,
                                                const int* __restrict__ rowstart,
                                                const int* __restrict__ cnt,
                                                const float* __restrict__ dinv,
                                                const float4* __restrict__ bias4,
                                                float4* __restrict__ OUT4, int n) {
    const int lane = threadIdx.x & 31;
    const int node = blockIdx.x * 8 + (threadIdx.x >> 5);
    if (node >= n) return;
    const int start = rowstart[node];
    const int m = cnt[node];
    const float di = dinv[node];
    const float dii = di * di;

    float4 b = bias4[lane];
    ushort4 h = H4[(size_t)node * 32 + lane];
    float ax = b.x + dii * bf2f(h.x);
    float ay = b.y + dii * bf2f(h.y);
    float az = b.z + dii * bf2f(h.z);
    float aw = b.w + dii * bf2f(h.w);

    int j = 0;
    for (; j + 4 <= m; j += 4) {
        const int base = start + j;
        int s0 = esrc[base + 0], s1 = esrc[base + 1];
        int s2 = esrc[base + 2], s3 = esrc[base + 3];
        float w0 = nrm[base + 0], w1 = nrm[base + 1];
        float w2 = nrm[base + 2], w3 = nrm[base + 3];
        ushort4 v0 = H4[(size_t)s0 * 32 + lane];
        ushort4 v1 = H4[(size_t)s1 * 32 + lane];
        ushort4 v2 = H4[(size_t)s2 * 32 + lane];
        ushort4 v3 = H4[(size_t)s3 * 32 + lane];
        ax += w0 * bf2f(v0.x); ay += w0 * bf2f(v0.y); az += w0 * bf2f(v0.z); aw += w0 * bf2f(v0.w);
        ax += w1 * bf2f(v1.x); ay += w1 * bf2f(v1.y); az += w1 * bf2f(v1.z); aw += w1 * bf2f(v1.w);
        ax += w2 * bf2f(v2.x); ay += w2 * bf2f(v2.y); az += w2 * bf2f(v2.z); aw += w2 * bf2f(v2.w);
        ax += w3 * bf2f(v3.x); ay += w3 * bf2f(v3.y); az += w3 * bf2f(v3.z); aw += w3 * bf2f(v3.w);
    }
    for (; j < m; ++j) {
        int s = esrc[start + j];
        float w = nrm[start + j];
        ushort4 v = H4[(size_t)s * 32 + lane];
        ax += w * bf2f(v.x); ay += w * bf2f(v.y); az += w * bf2f(v.z); aw += w * bf2f(v.w);
    }
    float4 o; o.x = ax; o.y = ay; o.z = az; o.w = aw;
    OUT4[(size_t)node * 32 + lane] = o;
}

extern "C" void kernel_launch(void* const* d_in, const int* in_sizes, int n_in,
                              void* d_out, int out_size, void* d_ws, size_t ws_size,
                              hipStream_t stream) {
    const float* x  = (const float*)d_in[0];
    const int*   ei = (const int*)d_in[1];    // [2,E] int32
    const float* ew = (const float*)d_in[2];
    const float* W1 = (const float*)d_in[3];
    const float* b1 = (const float*)d_in[4];
    const float* W2 = (const float*)d_in[5];
    const float* b2 = (const float*)d_in[6];
    float* out = (float*)d_out;

    const int N = in_sizes[0] / D;
    const int E = in_sizes[2];

    // workspace carve (256B aligned)
    char* p = (char*)d_ws;
    auto alloc = [&](size_t bytes) {
        void* r = (void*)p;
        p += (bytes + 255) & ~(size_t)255;
        return r;
    };
    unsigned long long* pk = (unsigned long long*)alloc((size_t)N * 8);
    float* dinv     = (float*)alloc((size_t)N * 4);
    int*   cnt      = (int*)alloc((size_t)N * 4);
    int*   rowstart = (int*)alloc((size_t)N * 4);
    int*   bsums    = (int*)alloc(1024 * 4);
    int*   boffs    = (int*)alloc(1024 * 4);
    int*   rank     = (int*)alloc((size_t)E * 4);
    int*   esrc     = (int*)alloc((size_t)E * 4);
    float* nrm      = (float*)alloc((size_t)E * 4);
    unsigned short* B1 = (unsigned short*)alloc((size_t)N * D * 2);  // H bf16
    float* B2       = (float*)alloc((size_t)N * D * 4);              // AGG1 f32

    const int nb = (N + 255) / 256;
    const int eb = (E + 255) / 256;
    const int gb = (N + 31) / 32;
    const int hb = (N + 7) / 8;

    hipMemsetAsync(pk, 0, (size_t)N * 8, stream);
    k_count<<<eb, 256, 0, stream>>>(ei, ew, pk, rank, E);
    k_scanA<<<nb, 256, 0, stream>>>(pk, rowstart, bsums, N);
    k_scanB<<<1, 256, 0, stream>>>(bsums, boffs, nb);
    k_scanC<<<nb, 256, 0, stream>>>(rowstart, boffs, pk, cnt, dinv, N);
    k_edges<<<eb, 256, 0, stream>>>(ei, ew, dinv, rowstart, rank, esrc, nrm, E);

    // layer 1
    k_gemm<<<gb, 256, 0, stream>>>(x, W1, B1, N, 0);
    k_gather<<<hb, 256, 0, stream>>>((const ushort4*)B1, esrc, nrm, rowstart, cnt, dinv,
                                     (const float4*)b1, (float4*)B2, N);
    // layer 2 (relu fused into GEMM input load)
    k_gemm<<<gb, 256, 0, stream>>>(B2, W2, B1, N, 1);
    k_gather<<<hb, 256, 0, stream>>>((const ushort4*)B1, esrc, nrm, rowstart, cnt, dinv,
                                     (const float4*)b2, (float4*)out, N);
}

// Round 5
// 243.516 us; speedup vs baseline: 1.9408x; 1.0467x over previous
//
#include <hip/hip_runtime.h>
#include <stdint.h>

#define D 128

typedef __bf16 bf16x8 __attribute__((ext_vector_type(8)));
typedef float f32x4 __attribute__((ext_vector_type(4)));

__device__ inline float bf2f(unsigned short u) {
    return __uint_as_float((unsigned)u << 16);
}
__device__ inline unsigned short f2bf(float f) {
    unsigned u = __float_as_uint(f);
    return (unsigned short)((u + 0x7FFF + ((u >> 16) & 1)) >> 16);  // RNE
}

// count edges per dst + accumulate weighted degree, ONE packed 64-bit atomic.
// high 32: count; low 32: sum(ew) in 2^-24 fixed point. Returned high = rank in bucket.
__global__ __launch_bounds__(256) void k_count(const int* __restrict__ ei,
                                               const float* __restrict__ ew,
                                               unsigned long long* __restrict__ pk,
                                               int* __restrict__ rank, int E) {
    int e = blockIdx.x * 256 + threadIdx.x;
    if (e < E) {
        int d = ei[E + e];
        unsigned int fx = (unsigned int)(ew[e] * 16777216.0f);
        unsigned long long old =
            atomicAdd(&pk[d], (1ULL << 32) | (unsigned long long)fx);
        rank[e] = (int)(old >> 32);
    }
}

// ---------------- 3-phase exclusive scan over packed counts ----------------
__global__ __launch_bounds__(256) void k_scanA(const unsigned long long* __restrict__ pk,
                                               int* rowstart, int* bsums, int n) {
    __shared__ int tmp[256];
    int tid = threadIdx.x;
    int i = blockIdx.x * 256 + tid;
    int v = (i < n) ? (int)(pk[i] >> 32) : 0;
    tmp[tid] = v;
    __syncthreads();
    for (int off = 1; off < 256; off <<= 1) {
        int t = (tid >= off) ? tmp[tid - off] : 0;
        __syncthreads();
        tmp[tid] += t;
        __syncthreads();
    }
    if (i < n) rowstart[i] = tmp[tid] - v;
    if (tid == 255) bsums[blockIdx.x] = tmp[255];
}

__global__ __launch_bounds__(256) void k_scanB(const int* __restrict__ bsums,
                                               int* boffs, int nb) {
    __shared__ int tmp[256];
    int tid = threadIdx.x;
    int v = (tid < nb) ? bsums[tid] : 0;
    tmp[tid] = v;
    __syncthreads();
    for (int off = 1; off < 256; off <<= 1) {
        int t = (tid >= off) ? tmp[tid - off] : 0;
        __syncthreads();
        tmp[tid] += t;
        __syncthreads();
    }
    if (tid < nb) boffs[tid] = tmp[tid] - v;
}

__global__ __launch_bounds__(256) void k_scanC(int* rowstart, const int* __restrict__ boffs,
                                               const unsigned long long* __restrict__ pk,
                                               int* cnt, float* dinv, int n) {
    int i = blockIdx.x * 256 + threadIdx.x;
    if (i < n) {
        rowstart[i] = rowstart[i] + boffs[blockIdx.x];
        unsigned long long v = pk[i];
        cnt[i] = (int)(v >> 32);
        float deg = 1.0f + (float)(unsigned int)(v & 0xFFFFFFFFu) * (1.0f / 16777216.0f);
        dinv[i] = rsqrtf(deg);
    }
}

// place edges into CSR: no atomics (position = rowstart[d] + rank[e]).
__global__ __launch_bounds__(256) void k_edges(const int* __restrict__ ei,
                                               const float* __restrict__ ew,
                                               const float* __restrict__ dinv,
                                               const int* __restrict__ rowstart,
                                               const int* __restrict__ rank,
                                               int* __restrict__ esrc,
                                               float* __restrict__ nrm, int E) {
    int e = blockIdx.x * 256 + threadIdx.x;
    if (e < E) {
        int s = ei[e];
        int d = ei[E + e];
        int p = rowstart[d] + rank[e];
        esrc[p] = s;
        nrm[p] = dinv[s] * ew[e] * dinv[d];
    }
}

// ---------------- W prep: Wt[n][k] = bf16(W[k][n]), 128x128, one block ----------------
__global__ __launch_bounds__(256) void k_prepW(const float* __restrict__ W,
                                               unsigned short* __restrict__ Wt) {
    __shared__ float t[128 * 132];
    int tid = threadIdx.x;
    for (int i = tid; i < 128 * 32; i += 256) {
        int r = i >> 5, c = i & 31;
        float4 v = *(const float4*)(W + r * 128 + c * 4);
        float* dp = &t[r * 132 + c * 4];
        dp[0] = v.x; dp[1] = v.y; dp[2] = v.z; dp[3] = v.w;
    }
    __syncthreads();
    for (int i = tid; i < 128 * 32; i += 256) {
        int nn = i >> 5, c = i & 31;  // 4 consecutive k's
        ushort4 o;
        o.x = f2bf(t[(c * 4 + 0) * 132 + nn]);
        o.y = f2bf(t[(c * 4 + 1) * 132 + nn]);
        o.z = f2bf(t[(c * 4 + 2) * 132 + nn]);
        o.w = f2bf(t[(c * 4 + 3) * 132 + nn]);
        *(ushort4*)(Wt + nn * 128 + c * 4) = o;
    }
}

// ---------------- MFMA GEMM: H(bf16) = X @ W ; X f32 or bf16 ----------------
// 256 thr = 4 waves; block computes 64 rows x 128 cols; K = 128 in 4 steps of 32.
template <bool IN_BF16>
__global__ __launch_bounds__(256) void k_mfma(const void* __restrict__ Xv,
                                              const unsigned short* __restrict__ Wt,
                                              unsigned short* __restrict__ H, int n) {
    __shared__ unsigned short sW[128 * 136];  // Wt rows (n-major), pad 136
    __shared__ unsigned short sX[64 * 136];   // X rows bf16, pad 136
    const int tid = threadIdx.x;
    const int row0 = blockIdx.x * 64;

    // stage W (bf16, already n-major)
    for (int i = tid; i < 128 * 16; i += 256) {
        int r = i >> 4, c = i & 15;
        *(int4*)(&sW[r * 136 + c * 8]) = *(const int4*)(Wt + r * 128 + c * 8);
    }
    // stage X
    if (IN_BF16) {
        const unsigned short* Xh = (const unsigned short*)Xv;
        for (int i = tid; i < 64 * 16; i += 256) {
            int r = i >> 4, c = i & 15;
            int gr = row0 + r;
            int4 v = make_int4(0, 0, 0, 0);
            if (gr < n) v = *(const int4*)(Xh + (size_t)gr * 128 + c * 8);
            *(int4*)(&sX[r * 136 + c * 8]) = v;
        }
    } else {
        const float* Xf = (const float*)Xv;
        for (int i = tid; i < 64 * 32; i += 256) {
            int r = i >> 5, c = i & 31;
            int gr = row0 + r;
            float4 v = make_float4(0.f, 0.f, 0.f, 0.f);
            if (gr < n) v = *(const float4*)(Xf + (size_t)gr * 128 + c * 4);
            ushort4 o;
            o.x = f2bf(v.x); o.y = f2bf(v.y); o.z = f2bf(v.z); o.w = f2bf(v.w);
            *(ushort4*)(&sX[r * 136 + c * 4]) = o;
        }
    }
    __syncthreads();

    const int lane = tid & 63;
    const int wv = tid >> 6;       // wave 0..3 -> rows wv*16..+15
    const int qm = lane & 15;
    const int quad = lane >> 4;    // 0..3

    f32x4 acc[8];
#pragma unroll
    for (int i = 0; i < 8; ++i) acc[i] = (f32x4){0.f, 0.f, 0.f, 0.f};

#pragma unroll
    for (int kb = 0; kb < 4; ++kb) {
        const int koff = kb * 32 + quad * 8;
        bf16x8 a = *(const bf16x8*)(&sX[(wv * 16 + qm) * 136 + koff]);
#pragma unroll
        for (int n0 = 0; n0 < 8; ++n0) {
            bf16x8 b = *(const bf16x8*)(&sW[(n0 * 16 + qm) * 136 + koff]);
            acc[n0] = __builtin_amdgcn_mfma_f32_16x16x32_bf16(a, b, acc[n0], 0, 0, 0);
        }
    }

    // epilogue: repack C through LDS (reuse sX) for coalesced 16B stores
    __syncthreads();
    unsigned short* sE = sX;
#pragma unroll
    for (int n0 = 0; n0 < 8; ++n0)
#pragma unroll
        for (int r = 0; r < 4; ++r)
            sE[(wv * 16 + quad * 4 + r) * 136 + n0 * 16 + qm] = f2bf(acc[n0][r]);
    __syncthreads();

    const int row_in = lane >> 2;      // 0..15
    const int c0 = (lane & 3) * 4;     // 4 chunks of 8 bf16 each
    const int grow = row0 + wv * 16 + row_in;
    if (grow < n) {
#pragma unroll
        for (int j = 0; j < 4; ++j)
            *(int4*)(H + (size_t)grow * 128 + (c0 + j) * 8) =
                *(const int4*)(&sE[(wv * 16 + row_in) * 136 + (c0 + j) * 8]);
    }
}

// ---------------- gather: OUT[d] = b + dinv[d]^2*H[d] + sum nrm*H[src] ----------------
// 8 nodes / 256-thr block; 32 thr/node; 4 bf16 cols (8B)/thread; x4 unroll.
// OUT_BF16: apply relu, store bf16 (layer 1). Else store f32 (final).
template <bool OUT_BF16>
__global__ __launch_bounds__(256) void k_gather(const ushort4* __restrict__ H4,
                                                const int* __restrict__ esrc,
                                                const float* __restrict__ nrm,
                                                const int* __restrict__ rowstart,
                                                const int* __restrict__ cnt,
                                                const float* __restrict__ dinv,
                                                const float4* __restrict__ bias4,
                                                void* __restrict__ OUTv, int n) {
    const int lane = threadIdx.x & 31;
    const int node = blockIdx.x * 8 + (threadIdx.x >> 5);
    if (node >= n) return;
    const int start = rowstart[node];
    const int m = cnt[node];
    const float di = dinv[node];
    const float dii = di * di;

    float4 b = bias4[lane];
    ushort4 h = H4[(size_t)node * 32 + lane];
    float ax = b.x + dii * bf2f(h.x);
    float ay = b.y + dii * bf2f(h.y);
    float az = b.z + dii * bf2f(h.z);
    float aw = b.w + dii * bf2f(h.w);

    int j = 0;
    for (; j + 4 <= m; j += 4) {
        const int base = start + j;
        int s0 = esrc[base + 0], s1 = esrc[base + 1];
        int s2 = esrc[base + 2], s3 = esrc[base + 3];
        float w0 = nrm[base + 0], w1 = nrm[base + 1];
        float w2 = nrm[base + 2], w3 = nrm[base + 3];
        ushort4 v0 = H4[(size_t)s0 * 32 + lane];
        ushort4 v1 = H4[(size_t)s1 * 32 + lane];
        ushort4 v2 = H4[(size_t)s2 * 32 + lane];
        ushort4 v3 = H4[(size_t)s3 * 32 + lane];
        ax += w0 * bf2f(v0.x); ay += w0 * bf2f(v0.y); az += w0 * bf2f(v0.z); aw += w0 * bf2f(v0.w);
        ax += w1 * bf2f(v1.x); ay += w1 * bf2f(v1.y); az += w1 * bf2f(v1.z); aw += w1 * bf2f(v1.w);
        ax += w2 * bf2f(v2.x); ay += w2 * bf2f(v2.y); az += w2 * bf2f(v2.z); aw += w2 * bf2f(v2.w);
        ax += w3 * bf2f(v3.x); ay += w3 * bf2f(v3.y); az += w3 * bf2f(v3.z); aw += w3 * bf2f(v3.w);
    }
    for (; j < m; ++j) {
        int s = esrc[start + j];
        float w = nrm[start + j];
        ushort4 v = H4[(size_t)s * 32 + lane];
        ax += w * bf2f(v.x); ay += w * bf2f(v.y); az += w * bf2f(v.z); aw += w * bf2f(v.w);
    }
    if (OUT_BF16) {
        ushort4 o;
        o.x = f2bf(fmaxf(ax, 0.f)); o.y = f2bf(fmaxf(ay, 0.f));
        o.z = f2bf(fmaxf(az, 0.f)); o.w = f2bf(fmaxf(aw, 0.f));
        ((ushort4*)OUTv)[(size_t)node * 32 + lane] = o;
    } else {
        float4 o; o.x = ax; o.y = ay; o.z = az; o.w = aw;
        ((float4*)OUTv)[(size_t)node * 32 + lane] = o;
    }
}

extern "C" void kernel_launch(void* const* d_in, const int* in_sizes, int n_in,
                              void* d_out, int out_size, void* d_ws, size_t ws_size,
                              hipStream_t stream) {
    const float* x  = (const float*)d_in[0];
    const int*   ei = (const int*)d_in[1];    // [2,E] int32
    const float* ew = (const float*)d_in[2];
    const float* W1 = (const float*)d_in[3];
    const float* b1 = (const float*)d_in[4];
    const float* W2 = (const float*)d_in[5];
    const float* b2 = (const float*)d_in[6];
    float* out = (float*)d_out;

    const int N = in_sizes[0] / D;
    const int E = in_sizes[2];

    char* p = (char*)d_ws;
    auto alloc = [&](size_t bytes) {
        void* r = (void*)p;
        p += (bytes + 255) & ~(size_t)255;
        return r;
    };
    unsigned long long* pk = (unsigned long long*)alloc((size_t)N * 8);
    float* dinv     = (float*)alloc((size_t)N * 4);
    int*   cnt      = (int*)alloc((size_t)N * 4);
    int*   rowstart = (int*)alloc((size_t)N * 4);
    int*   bsums    = (int*)alloc(1024 * 4);
    int*   boffs    = (int*)alloc(1024 * 4);
    int*   rank     = (int*)alloc((size_t)E * 4);
    int*   esrc     = (int*)alloc((size_t)E * 4);
    float* nrm      = (float*)alloc((size_t)E * 4);
    unsigned short* B1  = (unsigned short*)alloc((size_t)N * D * 2);  // H bf16
    unsigned short* B2h = (unsigned short*)alloc((size_t)N * D * 2);  // relu(agg1) bf16
    unsigned short* Wt1 = (unsigned short*)alloc(128 * 128 * 2);
    unsigned short* Wt2 = (unsigned short*)alloc(128 * 128 * 2);

    const int nb = (N + 255) / 256;
    const int eb = (E + 255) / 256;
    const int gb = (N + 63) / 64;
    const int hb = (N + 7) / 8;

    hipMemsetAsync(pk, 0, (size_t)N * 8, stream);
    k_prepW<<<1, 256, 0, stream>>>(W1, Wt1);
    k_prepW<<<1, 256, 0, stream>>>(W2, Wt2);
    k_count<<<eb, 256, 0, stream>>>(ei, ew, pk, rank, E);
    k_scanA<<<nb, 256, 0, stream>>>(pk, rowstart, bsums, N);
    k_scanB<<<1, 256, 0, stream>>>(bsums, boffs, nb);
    k_scanC<<<nb, 256, 0, stream>>>(rowstart, boffs, pk, cnt, dinv, N);
    k_edges<<<eb, 256, 0, stream>>>(ei, ew, dinv, rowstart, rank, esrc, nrm, E);

    // layer 1: H1 = x @ W1 (f32 in), gather -> relu -> bf16 B2h
    k_mfma<false><<<gb, 256, 0, stream>>>((const void*)x, Wt1, B1, N);
    k_gather<true><<<hb, 256, 0, stream>>>((const ushort4*)B1, esrc, nrm, rowstart, cnt,
                                           dinv, (const float4*)b1, (void*)B2h, N);
    // layer 2: H2 = B2h @ W2 (bf16 in), gather -> f32 out
    k_mfma<true><<<gb, 256, 0, stream>>>((const void*)B2h, Wt2, B1, N);
    k_gather<false><<<hb, 256, 0, stream>>>((const ushort4*)B1, esrc, nrm, rowstart, cnt,
                                            dinv, (const float4*)b2, (void*)out, N);
}

// Round 6
// 221.405 us; speedup vs baseline: 2.1346x; 1.0999x over previous
//
#include <hip/hip_runtime.h>
#include <stdint.h>

#define D 128

typedef __bf16 bf16x8 __attribute__((ext_vector_type(8)));
typedef float f32x4 __attribute__((ext_vector_type(4)));

__device__ inline float bf2f(unsigned short u) {
    return __uint_as_float((unsigned)u << 16);
}
__device__ inline unsigned short f2bf(float f) {
    unsigned u = __float_as_uint(f);
    return (unsigned short)((u + 0x7FFF + ((u >> 16) & 1)) >> 16);  // RNE
}

// ---------------- prep: blocks 0,1 transpose W1/W2 -> bf16 n-major; rest zero pk ----------------
__global__ __launch_bounds__(256) void k_prep(const float* __restrict__ W1,
                                              unsigned short* __restrict__ Wt1,
                                              const float* __restrict__ W2,
                                              unsigned short* __restrict__ Wt2,
                                              unsigned long long* __restrict__ pk, int n) {
    __shared__ float t[128 * 132];
    const int tid = threadIdx.x;
    if (blockIdx.x < 2) {
        const float* W = (blockIdx.x == 0) ? W1 : W2;
        unsigned short* Wt = (blockIdx.x == 0) ? Wt1 : Wt2;
        for (int i = tid; i < 128 * 32; i += 256) {
            int r = i >> 5, c = i & 31;
            float4 v = *(const float4*)(W + r * 128 + c * 4);
            float* dp = &t[r * 132 + c * 4];
            dp[0] = v.x; dp[1] = v.y; dp[2] = v.z; dp[3] = v.w;
        }
        __syncthreads();
        for (int i = tid; i < 128 * 32; i += 256) {
            int nn = i >> 5, c = i & 31;
            ushort4 o;
            o.x = f2bf(t[(c * 4 + 0) * 132 + nn]);
            o.y = f2bf(t[(c * 4 + 1) * 132 + nn]);
            o.z = f2bf(t[(c * 4 + 2) * 132 + nn]);
            o.w = f2bf(t[(c * 4 + 3) * 132 + nn]);
            *(ushort4*)(Wt + nn * 128 + c * 4) = o;
        }
    } else {
        int i = (blockIdx.x - 2) * 256 + tid;
        if (i < n) pk[i] = 0ULL;
    }
}

// ---------------- MFMA GEMM body: H(bf16) = X @ Wt^T over one 64-row tile ----------------
template <bool IN_BF16>
__device__ inline void mfma_body(unsigned short* sW, unsigned short* sX,
                                 const void* __restrict__ Xv,
                                 const unsigned short* __restrict__ Wt,
                                 unsigned short* __restrict__ H, int n, int blk) {
    const int tid = threadIdx.x;
    const int row0 = blk * 64;

    for (int i = tid; i < 128 * 16; i += 256) {
        int r = i >> 4, c = i & 15;
        *(int4*)(&sW[r * 136 + c * 8]) = *(const int4*)(Wt + r * 128 + c * 8);
    }
    if (IN_BF16) {
        const unsigned short* Xh = (const unsigned short*)Xv;
        for (int i = tid; i < 64 * 16; i += 256) {
            int r = i >> 4, c = i & 15;
            int gr = row0 + r;
            int4 v = make_int4(0, 0, 0, 0);
            if (gr < n) v = *(const int4*)(Xh + (size_t)gr * 128 + c * 8);
            *(int4*)(&sX[r * 136 + c * 8]) = v;
        }
    } else {
        const float* Xf = (const float*)Xv;
        for (int i = tid; i < 64 * 32; i += 256) {
            int r = i >> 5, c = i & 31;
            int gr = row0 + r;
            float4 v = make_float4(0.f, 0.f, 0.f, 0.f);
            if (gr < n) v = *(const float4*)(Xf + (size_t)gr * 128 + c * 4);
            ushort4 o;
            o.x = f2bf(v.x); o.y = f2bf(v.y); o.z = f2bf(v.z); o.w = f2bf(v.w);
            *(ushort4*)(&sX[r * 136 + c * 4]) = o;
        }
    }
    __syncthreads();

    const int lane = tid & 63;
    const int wv = tid >> 6;
    const int qm = lane & 15;
    const int quad = lane >> 4;

    f32x4 acc[8];
#pragma unroll
    for (int i = 0; i < 8; ++i) acc[i] = (f32x4){0.f, 0.f, 0.f, 0.f};

#pragma unroll
    for (int kb = 0; kb < 4; ++kb) {
        const int koff = kb * 32 + quad * 8;
        bf16x8 a = *(const bf16x8*)(&sX[(wv * 16 + qm) * 136 + koff]);
#pragma unroll
        for (int n0 = 0; n0 < 8; ++n0) {
            bf16x8 b = *(const bf16x8*)(&sW[(n0 * 16 + qm) * 136 + koff]);
            acc[n0] = __builtin_amdgcn_mfma_f32_16x16x32_bf16(a, b, acc[n0], 0, 0, 0);
        }
    }

    __syncthreads();
    unsigned short* sE = sX;
#pragma unroll
    for (int n0 = 0; n0 < 8; ++n0)
#pragma unroll
        for (int r = 0; r < 4; ++r)
            sE[(wv * 16 + quad * 4 + r) * 136 + n0 * 16 + qm] = f2bf(acc[n0][r]);
    __syncthreads();

    const int row_in = lane >> 2;
    const int c0 = (lane & 3) * 4;
    const int grow = row0 + wv * 16 + row_in;
    if (grow < n) {
#pragma unroll
        for (int j = 0; j < 4; ++j)
            *(int4*)(H + (size_t)grow * 128 + (c0 + j) * 8) =
                *(const int4*)(&sE[(wv * 16 + row_in) * 136 + (c0 + j) * 8]);
    }
}

// ---------------- FUSED: blocks [0,gb) mfma layer-1 (f32 in); blocks [gb,..) edge count ----------------
// count: one packed 64-bit atomic per edge. high 32 = count, low 32 = sum(ew) in 2^-24 fixed.
__global__ __launch_bounds__(256) void k_cm(const float* __restrict__ X,
                                            const unsigned short* __restrict__ Wt,
                                            unsigned short* __restrict__ H, int n, int gb,
                                            const int* __restrict__ ei,
                                            const float* __restrict__ ew,
                                            unsigned long long* __restrict__ pk,
                                            int* __restrict__ rank, int E) {
    __shared__ unsigned short sW[128 * 136];
    __shared__ unsigned short sX[64 * 136];
    if (blockIdx.x < gb) {
        mfma_body<false>(sW, sX, (const void*)X, Wt, H, n, blockIdx.x);
    } else {
        int e = (blockIdx.x - gb) * 256 + threadIdx.x;
        if (e < E) {
            int d = ei[E + e];
            unsigned int fx = (unsigned int)(ew[e] * 16777216.0f);
            unsigned long long old =
                atomicAdd(&pk[d], (1ULL << 32) | (unsigned long long)fx);
            rank[e] = (int)(old >> 32);
        }
    }
}

// standalone mfma for layer 2 (bf16 in)
__global__ __launch_bounds__(256) void k_mfma2(const unsigned short* __restrict__ X,
                                               const unsigned short* __restrict__ Wt,
                                               unsigned short* __restrict__ H, int n) {
    __shared__ unsigned short sW[128 * 136];
    __shared__ unsigned short sX[64 * 136];
    mfma_body<true>(sW, sX, (const void*)X, Wt, H, n, blockIdx.x);
}

// ---------------- scanA: per-block exclusive scan of counts + block sums ----------------
__global__ __launch_bounds__(256) void k_scanA(const unsigned long long* __restrict__ pk,
                                               int* rowstart, int* bsums, int n) {
    __shared__ int tmp[256];
    int tid = threadIdx.x;
    int i = blockIdx.x * 256 + tid;
    int v = (i < n) ? (int)(pk[i] >> 32) : 0;
    tmp[tid] = v;
    __syncthreads();
    for (int off = 1; off < 256; off <<= 1) {
        int t = (tid >= off) ? tmp[tid - off] : 0;
        __syncthreads();
        tmp[tid] += t;
        __syncthreads();
    }
    if (i < n) rowstart[i] = tmp[tid] - v;
    if (tid == 255) bsums[blockIdx.x] = tmp[255];
}

// ---------------- scanBC: each block sums bsums[0..b-1] itself, finalizes rowstart/cnt/dinv ----------------
__global__ __launch_bounds__(256) void k_scanBC(int* rowstart, const int* __restrict__ bsums,
                                                const unsigned long long* __restrict__ pk,
                                                int* cnt, float* dinv, int n) {
    __shared__ int sred[4];
    int tid = threadIdx.x;
    int v = (tid < (int)blockIdx.x) ? bsums[tid] : 0;   // grid = nb <= 256
#pragma unroll
    for (int off = 32; off; off >>= 1) v += __shfl_down(v, off);
    if ((tid & 63) == 0) sred[tid >> 6] = v;
    __syncthreads();
    int total = sred[0] + sred[1] + sred[2] + sred[3];
    int i = blockIdx.x * 256 + tid;
    if (i < n) {
        rowstart[i] += total;
        unsigned long long pv = pk[i];
        cnt[i] = (int)(pv >> 32);
        float deg = 1.0f + (float)(unsigned int)(pv & 0xFFFFFFFFu) * (1.0f / 16777216.0f);
        dinv[i] = rsqrtf(deg);
    }
}

// ---------------- edges: place packed (src, nrm) records; no atomics ----------------
__global__ __launch_bounds__(256) void k_edges(const int* __restrict__ ei,
                                               const float* __restrict__ ew,
                                               const float* __restrict__ dinv,
                                               const int* __restrict__ rowstart,
                                               const int* __restrict__ rank,
                                               int2* __restrict__ erec, int E) {
    int e = blockIdx.x * 256 + threadIdx.x;
    if (e < E) {
        int s = ei[e];
        int d = ei[E + e];
        int p = rowstart[d] + rank[e];
        float nm = dinv[s] * ew[e] * dinv[d];
        erec[p] = make_int2(s, __float_as_int(nm));
    }
}

// ---------------- gather: OUT[d] = b + dinv[d]^2*H[d] + sum nrm*H[src] ----------------
// 8 nodes / 256-thr block; 32 thr/node; 4 bf16 cols (8B)/thread; x4 unroll, packed int2 edge recs.
template <bool OUT_BF16>
__global__ __launch_bounds__(256) void k_gather(const ushort4* __restrict__ H4,
                                                const int2* __restrict__ erec,
                                                const int* __restrict__ rowstart,
                                                const int* __restrict__ cnt,
                                                const float* __restrict__ dinv,
                                                const float4* __restrict__ bias4,
                                                void* __restrict__ OUTv, int n) {
    const int lane = threadIdx.x & 31;
    const int node = blockIdx.x * 8 + (threadIdx.x >> 5);
    if (node >= n) return;
    const int start = rowstart[node];
    const int m = cnt[node];
    const float di = dinv[node];
    const float dii = di * di;

    float4 b = bias4[lane];
    ushort4 h = H4[(size_t)node * 32 + lane];
    float ax = b.x + dii * bf2f(h.x);
    float ay = b.y + dii * bf2f(h.y);
    float az = b.z + dii * bf2f(h.z);
    float aw = b.w + dii * bf2f(h.w);

    int j = 0;
    for (; j + 4 <= m; j += 4) {
        const int base = start + j;
        int2 e0 = erec[base + 0], e1 = erec[base + 1];
        int2 e2 = erec[base + 2], e3 = erec[base + 3];
        float w0 = __int_as_float(e0.y), w1 = __int_as_float(e1.y);
        float w2 = __int_as_float(e2.y), w3 = __int_as_float(e3.y);
        ushort4 v0 = H4[(size_t)e0.x * 32 + lane];
        ushort4 v1 = H4[(size_t)e1.x * 32 + lane];
        ushort4 v2 = H4[(size_t)e2.x * 32 + lane];
        ushort4 v3 = H4[(size_t)e3.x * 32 + lane];
        ax += w0 * bf2f(v0.x); ay += w0 * bf2f(v0.y); az += w0 * bf2f(v0.z); aw += w0 * bf2f(v0.w);
        ax += w1 * bf2f(v1.x); ay += w1 * bf2f(v1.y); az += w1 * bf2f(v1.z); aw += w1 * bf2f(v1.w);
        ax += w2 * bf2f(v2.x); ay += w2 * bf2f(v2.y); az += w2 * bf2f(v2.z); aw += w2 * bf2f(v2.w);
        ax += w3 * bf2f(v3.x); ay += w3 * bf2f(v3.y); az += w3 * bf2f(v3.z); aw += w3 * bf2f(v3.w);
    }
    for (; j < m; ++j) {
        int2 er = erec[start + j];
        float w = __int_as_float(er.y);
        ushort4 v = H4[(size_t)er.x * 32 + lane];
        ax += w * bf2f(v.x); ay += w * bf2f(v.y); az += w * bf2f(v.z); aw += w * bf2f(v.w);
    }
    if (OUT_BF16) {
        ushort4 o;
        o.x = f2bf(fmaxf(ax, 0.f)); o.y = f2bf(fmaxf(ay, 0.f));
        o.z = f2bf(fmaxf(az, 0.f)); o.w = f2bf(fmaxf(aw, 0.f));
        ((ushort4*)OUTv)[(size_t)node * 32 + lane] = o;
    } else {
        float4 o; o.x = ax; o.y = ay; o.z = az; o.w = aw;
        ((float4*)OUTv)[(size_t)node * 32 + lane] = o;
    }
}

extern "C" void kernel_launch(void* const* d_in, const int* in_sizes, int n_in,
                              void* d_out, int out_size, void* d_ws, size_t ws_size,
                              hipStream_t stream) {
    const float* x  = (const float*)d_in[0];
    const int*   ei = (const int*)d_in[1];    // [2,E] int32
    const float* ew = (const float*)d_in[2];
    const float* W1 = (const float*)d_in[3];
    const float* b1 = (const float*)d_in[4];
    const float* W2 = (const float*)d_in[5];
    const float* b2 = (const float*)d_in[6];
    float* out = (float*)d_out;

    const int N = in_sizes[0] / D;
    const int E = in_sizes[2];

    char* p = (char*)d_ws;
    auto alloc = [&](size_t bytes) {
        void* r = (void*)p;
        p += (bytes + 255) & ~(size_t)255;
        return r;
    };
    unsigned long long* pk = (unsigned long long*)alloc((size_t)N * 8);
    float* dinv     = (float*)alloc((size_t)N * 4);
    int*   cnt      = (int*)alloc((size_t)N * 4);
    int*   rowstart = (int*)alloc((size_t)N * 4);
    int*   bsums    = (int*)alloc(1024 * 4);
    int*   rank     = (int*)alloc((size_t)E * 4);
    int2*  erec     = (int2*)alloc((size_t)E * 8);
    unsigned short* B1  = (unsigned short*)alloc((size_t)N * D * 2);  // H bf16
    unsigned short* B2h = (unsigned short*)alloc((size_t)N * D * 2);  // relu(agg1) bf16
    unsigned short* Wt1 = (unsigned short*)alloc(128 * 128 * 2);
    unsigned short* Wt2 = (unsigned short*)alloc(128 * 128 * 2);

    const int nb = (N + 255) / 256;      // 196
    const int eb = (E + 255) / 256;      // 2344
    const int gb = (N + 63) / 64;        // 782
    const int hb = (N + 7) / 8;

    // 1. prep: W transposes + pk zero
    k_prep<<<2 + nb, 256, 0, stream>>>(W1, Wt1, W2, Wt2, pk, N);
    // 2. fused: mfma layer-1 || edge count
    k_cm<<<gb + eb, 256, 0, stream>>>(x, Wt1, B1, N, gb, ei, ew, pk, rank, E);
    // 3-4. scan
    k_scanA<<<nb, 256, 0, stream>>>(pk, rowstart, bsums, N);
    k_scanBC<<<nb, 256, 0, stream>>>(rowstart, bsums, pk, cnt, dinv, N);
    // 5. CSR fill
    k_edges<<<eb, 256, 0, stream>>>(ei, ew, dinv, rowstart, rank, erec, E);
    // 6. gather layer-1 -> relu -> bf16
    k_gather<true><<<hb, 256, 0, stream>>>((const ushort4*)B1, erec, rowstart, cnt,
                                           dinv, (const float4*)b1, (void*)B2h, N);
    // 7. mfma layer-2
    k_mfma2<<<gb, 256, 0, stream>>>(B2h, Wt2, B1, N);
    // 8. gather layer-2 -> f32 out
    k_gather<false><<<hb, 256, 0, stream>>>((const ushort4*)B1, erec, rowstart, cnt,
                                            dinv, (const float4*)b2, (void*)out, N);
}